// Round 2
// baseline (47.219 us; speedup 1.0000x reference)
//
#include <hip/hip_runtime.h>
#include <hip/hip_bf16.h>

#define MM 64
#define KTOT 4096
#define NN 11008
#define PACKS 1376    // NN / 8
#define BN 64
#define NBLK 172      // NN / BN
#define KSPLIT 8
#define BKCHUNK 512   // KTOT / KSPLIT
#define BK 64
#define NSTEP 8       // BKCHUNK / BK
#define NBLOCKS (NBLK * KSPLIT)  // 1376

typedef float f32x4 __attribute__((ext_vector_type(4)));
typedef short bf16x8 __attribute__((ext_vector_type(8)));

__device__ __forceinline__ unsigned int f2bf(float f) {
    unsigned int b = __float_as_uint(f);
    return (b + 0x7FFFu + ((b >> 16) & 1u)) >> 16;   // RNE to bf16
}
__device__ __forceinline__ int swz(int row) { return (row ^ (row >> 3)) & 7; }

// prep: init out with bias (rows broadcast) + convert x f32 -> bf16 into d_ws
__global__ __launch_bounds__(256) void prep(const float* __restrict__ x,
                                            const float* __restrict__ bias,
                                            float* __restrict__ out,
                                            unsigned short* __restrict__ xbf) {
    const int t = blockIdx.x * 256 + threadIdx.x;   // 688*256 = 176128 threads
    // out init: 176128 float4s
    {
        const int n = (t * 4) % NN;
        float4 b = *reinterpret_cast<const float4*>(bias + n);
        reinterpret_cast<float4*>(out)[t] = b;
    }
    // x convert: 262144 floats / 8 per thread = 32768 threads
    if (t < (MM * KTOT / 8)) {
        const float4 v0 = reinterpret_cast<const float4*>(x)[t * 2];
        const float4 v1 = reinterpret_cast<const float4*>(x)[t * 2 + 1];
        uint4 o;
        o.x = f2bf(v0.x) | (f2bf(v0.y) << 16);
        o.y = f2bf(v0.z) | (f2bf(v0.w) << 16);
        o.z = f2bf(v1.x) | (f2bf(v1.y) << 16);
        o.w = f2bf(v1.z) | (f2bf(v1.w) << 16);
        reinterpret_cast<uint4*>(xbf)[t] = o;
    }
}

__global__ __launch_bounds__(256) void awq_mfma(
    const unsigned short* __restrict__ xbf, const int* __restrict__ qw,
    const int* __restrict__ qz, const float* __restrict__ sc,
    float* __restrict__ out)
{
    __shared__ __attribute__((aligned(16))) unsigned short wt[2][BN * BK];

    const int tid  = threadIdx.x;
    const int lane = tid & 63;
    const int wg   = blockIdx.x;
    const int ks   = wg & 7;          // one k-stripe per XCD (round-robin dispatch)
    const int bn   = wg >> 3;         // ascending bn within an XCD -> qweight line reuse in L2
    const int n0   = bn * BN;
    const int c0   = bn * 8;
    const int k00  = ks * BKCHUNK;

    const int cl = tid & 7;           // pack-col 0..7
    const int aa = tid >> 3;          // k-pair 0..31

    const int wv  = tid >> 6;
    const int mb  = (wv & 1) * 32;
    const int nb  = (wv >> 1) * 32;
    const int l15 = lane & 15;
    const int l4  = lane >> 4;

    int q0r[2], q1r[2], zzr[2];
    float4 s0r[2], s1r[2];
    bf16x8 af[2][4];                  // A frags [set][mt*2+kk]

#define LOADQ(S, ST) do {                                              \
        const int k0_ = k00 + (ST) * BK;                               \
        const int g_  = k0_ >> 7;                                      \
        q0r[S] = qw[(k0_ + 2 * aa) * PACKS + c0 + cl];                 \
        q1r[S] = qw[(k0_ + 2 * aa + 1) * PACKS + c0 + cl];             \
        zzr[S] = qz[g_ * PACKS + c0 + cl];                             \
        s0r[S] = *reinterpret_cast<const float4*>(sc + g_ * NN + n0 + cl * 8);     \
        s1r[S] = *reinterpret_cast<const float4*>(sc + g_ * NN + n0 + cl * 8 + 4); \
    } while (0)

#define LOADA(S, ST) do {                                              \
        const int k0_ = k00 + (ST) * BK;                               \
        _Pragma("unroll")                                              \
        for (int mt = 0; mt < 2; ++mt)                                 \
            _Pragma("unroll")                                          \
            for (int kk = 0; kk < 2; ++kk)                             \
                af[S][mt * 2 + kk] = *reinterpret_cast<const bf16x8*>( \
                    xbf + (mb + mt * 16 + l15) * KTOT + k0_ + kk * 32 + l4 * 8); \
    } while (0)

    f32x4 acc[2][2] = {};

    LOADQ(0, 0);
    LOADA(0, 0);

#pragma unroll
    for (int st = 0; st < NSTEP; ++st) {
        const int cur = st & 1, nxt = cur ^ 1;

        // issue next step's global loads early: overlap with dequant + LDS write + MFMA
        if (st < NSTEP - 1) {
            LOADQ(nxt, st + 1);
            LOADA(nxt, st + 1);
        }

        // ---- dequant current (AWQ nibble order: shift = (j>>1)*4 + (j&1)*16) ----
        {
            const int q0 = q0r[cur], q1 = q1r[cur], zz = zzr[cur];
            const float sj[8] = { s0r[cur].x, s0r[cur].y, s0r[cur].z, s0r[cur].w,
                                  s1r[cur].x, s1r[cur].y, s1r[cur].z, s1r[cur].w };
            unsigned int pair[8];
#pragma unroll
            for (int j = 0; j < 8; ++j) {
                const int sh = ((j >> 1) << 2) + ((j & 1) << 4);
                const int zj = (zz >> sh) & 0xF;
                const float nzs = -(float)zj * sj[j];
                const float w0 = fmaf((float)((q0 >> sh) & 0xF), sj[j], nzs);
                const float w1 = fmaf((float)((q1 >> sh) & 0xF), sj[j], nzs);
                unsigned int pr;
                asm("v_cvt_pk_bf16_f32 %0, %1, %2" : "=v"(pr) : "v"(w0), "v"(w1));
                pair[j] = pr;          // low = k even, high = k odd
            }
            // ---- LDS write (double buffer) ----
#pragma unroll
            for (int j = 0; j < 8; ++j) {
                const int row = cl * 8 + j;
                const int col = 2 * aa;
                const int idx = row * 64 + (((col >> 3) ^ swz(row)) << 3) + (col & 7);
                *reinterpret_cast<unsigned int*>(&wt[cur][idx]) = pair[j];
            }
        }

        // one barrier per step: drain LDS only, leave global prefetch in flight
        asm volatile("s_waitcnt lgkmcnt(0)\n\ts_barrier" ::: "memory");

        // ---- MFMA ----
#pragma unroll
        for (int kk = 0; kk < 2; ++kk) {
            bf16x8 bfr[2];
#pragma unroll
            for (int nt = 0; nt < 2; ++nt) {
                const int row  = nb + nt * 16 + l15;
                const int slot = kk * 4 + l4;
                bfr[nt] = *reinterpret_cast<const bf16x8*>(
                    &wt[cur][row * 64 + ((slot ^ swz(row)) << 3)]);
            }
#pragma unroll
            for (int mt = 0; mt < 2; ++mt)
#pragma unroll
                for (int nt = 0; nt < 2; ++nt)
                    acc[mt][nt] = __builtin_amdgcn_mfma_f32_16x16x32_bf16(
                        af[cur][mt * 2 + kk], bfr[nt], acc[mt][nt], 0, 0, 0);
        }
    }

    // ---- epilogue: atomic accumulate partials (C/D: col=lane&15, row=(lane>>4)*4+r) ----
#pragma unroll
    for (int mt = 0; mt < 2; ++mt)
#pragma unroll
        for (int nt = 0; nt < 2; ++nt) {
            const int r0 = mb + mt * 16 + l4 * 4;
            const int cc = n0 + nb + nt * 16 + l15;
#pragma unroll
            for (int r = 0; r < 4; ++r)
                atomicAdd(&out[(r0 + r) * NN + cc], acc[mt][nt][r]);
        }
#undef LOADQ
#undef LOADA
}

extern "C" void kernel_launch(void* const* d_in, const int* in_sizes, int n_in,
                              void* d_out, int out_size, void* d_ws, size_t ws_size,
                              hipStream_t stream) {
    const float* x    = (const float*)d_in[0];
    const int*   qw   = (const int*)d_in[1];
    const int*   qz   = (const int*)d_in[2];
    const float* sc   = (const float*)d_in[3];
    const float* bias = (const float*)d_in[4];
    float* out = (float*)d_out;
    unsigned short* xbf = (unsigned short*)d_ws;   // 64*4096*2 = 512 KB

    prep<<<dim3((MM * NN / 4) / 256), 256, 0, stream>>>(x, bias, out, xbf);
    awq_mfma<<<dim3(NBLOCKS), 256, 0, stream>>>(xbf, qw, qz, sc, out);
}

// Round 3
// 45.581 us; speedup vs baseline: 1.0359x; 1.0359x over previous
//
#include <hip/hip_runtime.h>
#include <hip/hip_bf16.h>

#define MM 64
#define KTOT 4096
#define NN 11008
#define PACKS 1376    // NN / 8
#define BN 64
#define NBLK 172      // NN / BN
#define KSPLIT 8
#define BKCHUNK 512   // KTOT / KSPLIT
#define BK 64
#define NSTEP 8       // BKCHUNK / BK
#define NBLOCKS (NBLK * KSPLIT)  // 1376

typedef float f32x4 __attribute__((ext_vector_type(4)));
typedef short bf16x8 __attribute__((ext_vector_type(8)));

__device__ __forceinline__ unsigned int f2bf(float f) {
    unsigned int b = __float_as_uint(f);
    return (b + 0x7FFFu + ((b >> 16) & 1u)) >> 16;   // RNE to bf16
}
__device__ __forceinline__ int swz(int row) { return (row ^ (row >> 3)) & 7; }

// prep: convert x f32 -> bf16 into d_ws (512 KB)
__global__ __launch_bounds__(256) void prep(const float* __restrict__ x,
                                            unsigned short* __restrict__ xbf) {
    const int t = blockIdx.x * 256 + threadIdx.x;   // 128*256 = 32768 threads
    const float4 v0 = reinterpret_cast<const float4*>(x)[t * 2];
    const float4 v1 = reinterpret_cast<const float4*>(x)[t * 2 + 1];
    uint4 o;
    o.x = f2bf(v0.x) | (f2bf(v0.y) << 16);
    o.y = f2bf(v0.z) | (f2bf(v0.w) << 16);
    o.z = f2bf(v1.x) | (f2bf(v1.y) << 16);
    o.w = f2bf(v1.z) | (f2bf(v1.w) << 16);
    reinterpret_cast<uint4*>(xbf)[t] = o;
}

__global__ __launch_bounds__(256) void awq_mfma(
    const unsigned short* __restrict__ xbf, const int* __restrict__ qw,
    const int* __restrict__ qz, const float* __restrict__ sc,
    float* __restrict__ part)
{
    __shared__ __attribute__((aligned(16))) unsigned short wt[2][BN * BK];

    const int tid  = threadIdx.x;
    const int lane = tid & 63;
    const int wg   = blockIdx.x;
    const int ks   = wg & 7;          // one k-stripe per XCD (round-robin dispatch)
    const int bn   = wg >> 3;         // ascending bn within an XCD -> qweight line reuse in L2
    const int n0   = bn * BN;
    const int c0   = bn * 8;
    const int k00  = ks * BKCHUNK;

    const int cl = tid & 7;           // pack-col 0..7
    const int aa = tid >> 3;          // k-pair 0..31

    const int wv  = tid >> 6;
    const int mb  = (wv & 1) * 32;
    const int nb  = (wv >> 1) * 32;
    const int l15 = lane & 15;
    const int l4  = lane >> 4;

    int q0r[2], q1r[2], zzr[2];
    float4 s0r[2], s1r[2];
    bf16x8 af[2][4];                  // A frags [set][mt*2+kk]

#define LOADQ(S, ST) do {                                              \
        const int k0_ = k00 + (ST) * BK;                               \
        const int g_  = k0_ >> 7;                                      \
        q0r[S] = qw[(k0_ + 2 * aa) * PACKS + c0 + cl];                 \
        q1r[S] = qw[(k0_ + 2 * aa + 1) * PACKS + c0 + cl];             \
        zzr[S] = qz[g_ * PACKS + c0 + cl];                             \
        s0r[S] = *reinterpret_cast<const float4*>(sc + g_ * NN + n0 + cl * 8);     \
        s1r[S] = *reinterpret_cast<const float4*>(sc + g_ * NN + n0 + cl * 8 + 4); \
    } while (0)

#define LOADA(S, ST) do {                                              \
        const int k0_ = k00 + (ST) * BK;                               \
        _Pragma("unroll")                                              \
        for (int mt = 0; mt < 2; ++mt)                                 \
            _Pragma("unroll")                                          \
            for (int kk = 0; kk < 2; ++kk)                             \
                af[S][mt * 2 + kk] = *reinterpret_cast<const bf16x8*>( \
                    xbf + (mb + mt * 16 + l15) * KTOT + k0_ + kk * 32 + l4 * 8); \
    } while (0)

    f32x4 acc[2][2] = {};

    LOADQ(0, 0);
    LOADA(0, 0);

#pragma unroll
    for (int st = 0; st < NSTEP; ++st) {
        const int cur = st & 1, nxt = cur ^ 1;

        // issue next step's global loads early: overlap with dequant + LDS write + MFMA
        if (st < NSTEP - 1) {
            LOADQ(nxt, st + 1);
            LOADA(nxt, st + 1);
        }

        // ---- dequant current (AWQ nibble order: shift = (j>>1)*4 + (j&1)*16) ----
        {
            const int q0 = q0r[cur], q1 = q1r[cur], zz = zzr[cur];
            const float sj[8] = { s0r[cur].x, s0r[cur].y, s0r[cur].z, s0r[cur].w,
                                  s1r[cur].x, s1r[cur].y, s1r[cur].z, s1r[cur].w };
            unsigned int pair[8];
#pragma unroll
            for (int j = 0; j < 8; ++j) {
                const int sh = ((j >> 1) << 2) + ((j & 1) << 4);
                const int zj = (zz >> sh) & 0xF;
                const float nzs = -(float)zj * sj[j];
                const float w0 = fmaf((float)((q0 >> sh) & 0xF), sj[j], nzs);
                const float w1 = fmaf((float)((q1 >> sh) & 0xF), sj[j], nzs);
                unsigned int pr;
                asm("v_cvt_pk_bf16_f32 %0, %1, %2" : "=v"(pr) : "v"(w0), "v"(w1));
                pair[j] = pr;          // low = k even, high = k odd
            }
            // ---- LDS write (double buffer) ----
#pragma unroll
            for (int j = 0; j < 8; ++j) {
                const int row = cl * 8 + j;
                const int col = 2 * aa;
                const int idx = row * 64 + (((col >> 3) ^ swz(row)) << 3) + (col & 7);
                *reinterpret_cast<unsigned int*>(&wt[cur][idx]) = pair[j];
            }
        }

        // one barrier per step: drain LDS only, leave global prefetch in flight
        asm volatile("s_waitcnt lgkmcnt(0)\n\ts_barrier" ::: "memory");

        // ---- MFMA ----
#pragma unroll
        for (int kk = 0; kk < 2; ++kk) {
            bf16x8 bfr[2];
#pragma unroll
            for (int nt = 0; nt < 2; ++nt) {
                const int row  = nb + nt * 16 + l15;
                const int slot = kk * 4 + l4;
                bfr[nt] = *reinterpret_cast<const bf16x8*>(
                    &wt[cur][row * 64 + ((slot ^ swz(row)) << 3)]);
            }
#pragma unroll
            for (int mt = 0; mt < 2; ++mt)
#pragma unroll
                for (int nt = 0; nt < 2; ++nt)
                    acc[mt][nt] = __builtin_amdgcn_mfma_f32_16x16x32_bf16(
                        af[cur][mt * 2 + kk], bfr[nt], acc[mt][nt], 0, 0, 0);
        }
    }

    // ---- epilogue: plain stores of the partial tile (no atomics) ----
    float* pout = part + ks * (MM * NN);
#pragma unroll
    for (int mt = 0; mt < 2; ++mt)
#pragma unroll
        for (int nt = 0; nt < 2; ++nt) {
            const int r0 = mb + mt * 16 + l4 * 4;
            const int cc = n0 + nb + nt * 16 + l15;
#pragma unroll
            for (int r = 0; r < 4; ++r)
                pout[(r0 + r) * NN + cc] = acc[mt][nt][r];
        }
#undef LOADQ
#undef LOADA
}

// reduce: out = bias + sum_ks part[ks]
__global__ __launch_bounds__(256) void reduce_k(const float* __restrict__ part,
                                                const float* __restrict__ bias,
                                                float* __restrict__ out) {
    const int t = blockIdx.x * 256 + threadIdx.x;   // float4 idx, 176128 total
    const int n = (t * 4) % NN;
    float4 s = reinterpret_cast<const float4*>(part)[t];
#pragma unroll
    for (int ks = 1; ks < KSPLIT; ++ks) {
        const float4 v = reinterpret_cast<const float4*>(part + ks * (MM * NN))[t];
        s.x += v.x; s.y += v.y; s.z += v.z; s.w += v.w;
    }
    const float4 b = *reinterpret_cast<const float4*>(bias + n);
    s.x += b.x; s.y += b.y; s.z += b.z; s.w += b.w;
    reinterpret_cast<float4*>(out)[t] = s;
}

extern "C" void kernel_launch(void* const* d_in, const int* in_sizes, int n_in,
                              void* d_out, int out_size, void* d_ws, size_t ws_size,
                              hipStream_t stream) {
    const float* x    = (const float*)d_in[0];
    const int*   qw   = (const int*)d_in[1];
    const int*   qz   = (const int*)d_in[2];
    const float* sc   = (const float*)d_in[3];
    const float* bias = (const float*)d_in[4];
    float* out = (float*)d_out;

    unsigned short* xbf = (unsigned short*)d_ws;                       // 512 KB
    float* part = (float*)((char*)d_ws + MM * KTOT * sizeof(unsigned short)); // 22.5 MB

    prep<<<dim3(MM * KTOT / 8 / 256), 256, 0, stream>>>(x, xbf);
    awq_mfma<<<dim3(NBLOCKS), 256, 0, stream>>>(xbf, qw, qz, sc, part);
    reduce_k<<<dim3(MM * NN / 4 / 256), 256, 0, stream>>>(part, bias, out);
}

// Round 4
// 45.120 us; speedup vs baseline: 1.0465x; 1.0102x over previous
//
#include <hip/hip_runtime.h>
#include <hip/hip_bf16.h>

#define MM 64
#define KTOT 4096
#define NN 11008
#define PACKS 1376    // NN / 8
#define KSPLIT 8
#define BKCHUNK 512   // KTOT / KSPLIT
#define BK 64         // k per step
#define NSTEP 8       // BKCHUNK / BK
#define NBLOCKS 688   // 86 strip-groups * 8 ks ; 4 waves/block -> 344 strips

typedef float f32x4 __attribute__((ext_vector_type(4)));
typedef short bf16x8 __attribute__((ext_vector_type(8)));

__device__ __forceinline__ unsigned int f2bf(float f) {
    unsigned int b = __float_as_uint(f);
    return (b + 0x7FFFu + ((b >> 16) & 1u)) >> 16;   // RNE to bf16
}
__device__ __forceinline__ int swz(int r) { return (r ^ (r >> 3)) & 7; }

// prep: convert x f32 -> bf16 into d_ws (512 KB)
__global__ __launch_bounds__(256) void prep(const float* __restrict__ x,
                                            unsigned short* __restrict__ xbf) {
    const int t = blockIdx.x * 256 + threadIdx.x;   // 32768 threads
    const float4 v0 = reinterpret_cast<const float4*>(x)[t * 2];
    const float4 v1 = reinterpret_cast<const float4*>(x)[t * 2 + 1];
    uint4 o;
    o.x = f2bf(v0.x) | (f2bf(v0.y) << 16);
    o.y = f2bf(v0.z) | (f2bf(v0.w) << 16);
    o.z = f2bf(v1.x) | (f2bf(v1.y) << 16);
    o.w = f2bf(v1.z) | (f2bf(v1.w) << 16);
    reinterpret_cast<uint4*>(xbf)[t] = o;
}

// Barrier-free AWQ GEMM: each wave owns a 32n x 512k job, private LDS tile.
__global__ __launch_bounds__(256, 3) void awq_mfma(
    const unsigned short* __restrict__ xbf, const int* __restrict__ qw,
    const int* __restrict__ qz, const float* __restrict__ sc,
    float* __restrict__ part)
{
    // 4 waves x double-buffer x [32 n][64 k] bf16 = 32 KB
    __shared__ __attribute__((aligned(16))) unsigned short wt[4][2][32 * 64];

    const int tid  = threadIdx.x;
    const int wv   = tid >> 6;
    const int lane = tid & 63;
    const int bid  = blockIdx.x;
    const int ks   = bid & 7;            // k-stripe == XCD (round-robin dispatch)
    const int sb   = bid >> 3;           // 0..85
    const int strip = sb * 4 + wv;       // 0..343
    const int n0   = strip * 32;
    const int c0   = strip * 4;          // pack-column base (4 int32 per 32 cols)
    const int k00  = ks * BKCHUNK;

    const int cl  = lane & 3;            // pack col 0..3
    const int aa  = lane >> 2;           // k-pair 0..15
    const int l15 = lane & 15;
    const int l4  = lane >> 4;

    unsigned short (*my)[32 * 64] = wt[wv];

    const int* qbase = qw + c0 + cl;
    int q[2][4];                         // 2-deep prefetch ring
#define LOADQ(S, ST) do {                                              \
        const int* p_ = qbase + (k00 + (ST) * BK + 2 * aa) * PACKS;    \
        q[S][0] = p_[0];                                               \
        q[S][1] = p_[PACKS];                                           \
        q[S][2] = p_[32 * PACKS];                                      \
        q[S][3] = p_[33 * PACKS];                                      \
    } while (0)

    int zzn; float4 s0n, s1n;            // 1-deep scale/zero prefetch
#define LOADS(ST) do {                                                 \
        const int g_ = (k00 + (ST) * BK) >> 7;                         \
        zzn = qz[g_ * PACKS + c0 + cl];                                \
        s0n = *reinterpret_cast<const float4*>(sc + g_ * NN + (c0 + cl) * 8);     \
        s1n = *reinterpret_cast<const float4*>(sc + g_ * NN + (c0 + cl) * 8 + 4); \
    } while (0)

    float sj[8], nzs[8];
    f32x4 acc[4][2] = {};

    LOADS(0);
    LOADQ(0, 0);
    LOADQ(1, 1);

#pragma unroll
    for (int st = 0; st < NSTEP; ++st) {
        const int slot = st & 1;

        // expand group scales/zeros every 2 steps (GROUP_SIZE=128, BK=64)
        if ((st & 1) == 0) {
            const int zz = zzn;
            const float sjl[8] = { s0n.x, s0n.y, s0n.z, s0n.w,
                                   s1n.x, s1n.y, s1n.z, s1n.w };
#pragma unroll
            for (int j = 0; j < 8; ++j) {
                const int sh = ((j >> 1) << 2) + ((j & 1) << 4);
                sj[j]  = sjl[j];
                nzs[j] = -(float)((zz >> sh) & 0xF) * sjl[j];
            }
        }

        // grab current q, then refill ring 2 steps ahead (vmcnt never drains to 0)
        const int qA0 = q[slot][0], qA1 = q[slot][1];
        const int qB0 = q[slot][2], qB1 = q[slot][3];
        if (st + 2 < NSTEP) LOADQ(slot, st + 2);
        if ((st & 1) == 1 && st + 1 < NSTEP) LOADS(st + 1);

        // A fragments for this step, issued early (L2-hot; covered by dequant)
        bf16x8 af[4][2];
        {
            const unsigned short* xk = xbf + k00 + st * BK;
#pragma unroll
            for (int mt = 0; mt < 4; ++mt)
#pragma unroll
                for (int kg = 0; kg < 2; ++kg)
                    af[mt][kg] = *reinterpret_cast<const bf16x8*>(
                        xk + (mt * 16 + l15) * KTOT + kg * 32 + l4 * 8);
        }

        // ---- dequant (AWQ nibble order: shift = (j>>1)*4 + (j&1)*16) ----
        unsigned int pA[8], pB[8];
#pragma unroll
        for (int j = 0; j < 8; ++j) {
            const int sh = ((j >> 1) << 2) + ((j & 1) << 4);
            const float a0 = fmaf((float)((qA0 >> sh) & 0xF), sj[j], nzs[j]);
            const float a1 = fmaf((float)((qA1 >> sh) & 0xF), sj[j], nzs[j]);
            const float b0 = fmaf((float)((qB0 >> sh) & 0xF), sj[j], nzs[j]);
            const float b1 = fmaf((float)((qB1 >> sh) & 0xF), sj[j], nzs[j]);
            asm("v_cvt_pk_bf16_f32 %0, %1, %2" : "=v"(pA[j]) : "v"(a0), "v"(a1));
            asm("v_cvt_pk_bf16_f32 %0, %1, %2" : "=v"(pB[j]) : "v"(b0), "v"(b1));
        }

        // ---- private-LDS writes (no barrier: same wave reads it back) ----
        unsigned short* buf = my[slot];
#pragma unroll
        for (int j = 0; j < 8; ++j) {
            const int row = cl * 8 + j;
            const int sw  = swz(row);
            const int colA = 2 * aa;          // k 0..31 (pairs)
            const int colB = 32 + 2 * aa;     // k 32..63
            *reinterpret_cast<unsigned int*>(
                &buf[row * 64 + (((colA >> 3) ^ sw) << 3) + (colA & 7)]) = pA[j];
            *reinterpret_cast<unsigned int*>(
                &buf[row * 64 + (((colB >> 3) ^ sw) << 3) + (colB & 7)]) = pB[j];
        }

        // ---- B frags + MFMA (compiler inserts lgkm waits; wave-local only) ----
#pragma unroll
        for (int kg = 0; kg < 2; ++kg) {
            bf16x8 bfr[2];
#pragma unroll
            for (int nt = 0; nt < 2; ++nt) {
                const int row  = nt * 16 + l15;
                const int sl   = kg * 4 + l4;
                bfr[nt] = *reinterpret_cast<const bf16x8*>(
                    &buf[row * 64 + ((sl ^ swz(row)) << 3)]);
            }
#pragma unroll
            for (int mt = 0; mt < 4; ++mt) {
                acc[mt][0] = __builtin_amdgcn_mfma_f32_16x16x32_bf16(
                    af[mt][kg], bfr[0], acc[mt][0], 0, 0, 0);
                acc[mt][1] = __builtin_amdgcn_mfma_f32_16x16x32_bf16(
                    af[mt][kg], bfr[1], acc[mt][1], 0, 0, 0);
            }
        }
    }

    // ---- epilogue: plain stores (C/D: col=lane&15, row=(lane>>4)*4+r) ----
    float* pout = part + ks * (MM * NN) + n0;
#pragma unroll
    for (int mt = 0; mt < 4; ++mt)
#pragma unroll
        for (int nt = 0; nt < 2; ++nt) {
            const int r0 = mt * 16 + l4 * 4;
#pragma unroll
            for (int r = 0; r < 4; ++r)
                pout[(r0 + r) * NN + nt * 16 + l15] = acc[mt][nt][r];
        }
#undef LOADQ
#undef LOADS
}

// reduce: out = bias + sum_ks part[ks]
__global__ __launch_bounds__(256) void reduce_k(const float* __restrict__ part,
                                                const float* __restrict__ bias,
                                                float* __restrict__ out) {
    const int t = blockIdx.x * 256 + threadIdx.x;   // float4 idx, 176128 total
    const int n = (t * 4) % NN;
    float4 s = reinterpret_cast<const float4*>(part)[t];
#pragma unroll
    for (int ks = 1; ks < KSPLIT; ++ks) {
        const float4 v = reinterpret_cast<const float4*>(part + ks * (MM * NN))[t];
        s.x += v.x; s.y += v.y; s.z += v.z; s.w += v.w;
    }
    const float4 b = *reinterpret_cast<const float4*>(bias + n);
    s.x += b.x; s.y += b.y; s.z += b.z; s.w += b.w;
    reinterpret_cast<float4*>(out)[t] = s;
}

extern "C" void kernel_launch(void* const* d_in, const int* in_sizes, int n_in,
                              void* d_out, int out_size, void* d_ws, size_t ws_size,
                              hipStream_t stream) {
    const float* x    = (const float*)d_in[0];
    const int*   qw   = (const int*)d_in[1];
    const int*   qz   = (const int*)d_in[2];
    const float* sc   = (const float*)d_in[3];
    const float* bias = (const float*)d_in[4];
    float* out = (float*)d_out;

    unsigned short* xbf = (unsigned short*)d_ws;                                  // 512 KB
    float* part = (float*)((char*)d_ws + MM * KTOT * sizeof(unsigned short));     // 22.5 MB

    prep<<<dim3(MM * KTOT / 8 / 256), 256, 0, stream>>>(x, xbf);
    awq_mfma<<<dim3(NBLOCKS), 256, 0, stream>>>(xbf, qw, qz, sc, part);
    reduce_k<<<dim3(MM * NN / 4 / 256), 256, 0, stream>>>(part, bias, out);
}

// Round 5
// 32.180 us; speedup vs baseline: 1.4673x; 1.4021x over previous
//
#include <hip/hip_runtime.h>
#include <hip/hip_bf16.h>

#define MM 64
#define KTOT 4096
#define NN 11008
#define PACKS 1376    // NN / 8
#define BN 128
#define NBLK 86       // NN / BN
#define KSPLIT 8
#define BKCHUNK 512   // KTOT / KSPLIT
#define BK 32         // k per step
#define NSTEP 16      // BKCHUNK / BK
#define NBLOCKS (NBLK * KSPLIT)  // 688

typedef float f32x4 __attribute__((ext_vector_type(4)));
typedef short bf16x8 __attribute__((ext_vector_type(8)));

__device__ __forceinline__ unsigned int f2bf(float f) {
    unsigned int b = __float_as_uint(f);
    return (b + 0x7FFFu + ((b >> 16) & 1u)) >> 16;   // RNE to bf16
}

// prep: convert x f32 -> bf16 into d_ws (512 KB)
__global__ __launch_bounds__(256) void prep(const float* __restrict__ x,
                                            unsigned short* __restrict__ xbf) {
    const int t = blockIdx.x * 256 + threadIdx.x;   // 32768 threads
    const float4 v0 = reinterpret_cast<const float4*>(x)[t * 2];
    const float4 v1 = reinterpret_cast<const float4*>(x)[t * 2 + 1];
    uint4 o;
    o.x = f2bf(v0.x) | (f2bf(v0.y) << 16);
    o.y = f2bf(v0.z) | (f2bf(v0.w) << 16);
    o.z = f2bf(v1.x) | (f2bf(v1.y) << 16);
    o.w = f2bf(v1.z) | (f2bf(v1.w) << 16);
    reinterpret_cast<uint4*>(xbf)[t] = o;
}

// Coalesced-staging AWQ GEMM: global loads are dense block-cooperative row
// segments; LDS staging decouples them from the compute-side access pattern.
__global__ __launch_bounds__(256, 2) void awq_mfma(
    const unsigned short* __restrict__ xbf, const int* __restrict__ qw,
    const int* __restrict__ qz, const float* __restrict__ sc,
    float* __restrict__ part)
{
    // raw qweight staging: [dbuf][32 k-rows][16 dwords + 2 pad]
    __shared__ __attribute__((aligned(16))) unsigned int qst[2][32][18];
    // x tile: [dbuf][64 m-rows][16 dwords] (4 slots of 16B, XOR-swizzled)
    __shared__ __attribute__((aligned(16))) unsigned int xst[2][64][16];
    // dequanted W tiles, wave-private: [wave][dbuf][32 n][16 dwords swizzled]
    __shared__ __attribute__((aligned(16))) unsigned int wtl[4][2][32][16];

    const int tid = threadIdx.x, wv = tid >> 6, l = tid & 63;
    const int bid = blockIdx.x;
    const int ks  = bid & 7;            // k-stripe == XCD (round-robin dispatch)
    const int bn  = bid >> 3;           // adjacent bn share qweight lines on one XCD
    const int k00 = ks * BKCHUNK;
    const int l15 = l & 15, l4 = l >> 4;

    // block-cooperative staging mappings
    const int qrow = tid >> 3, qdw = (tid & 7) * 2;   // 32 rows x 16 dwords (64B dense)
    const int xrow = tid >> 2, xsl = tid & 3;         // 64 rows x 4 slots of 16B
    // wave-local dequant mapping: k-pair t2, pack-col pc within wave's n-range
    const int t2 = l >> 2, pc = l & 3;
    const int cg = bn * 16 + wv * 4 + pc;             // global pack-col

    const int* qsrc = qw + (k00 + qrow) * PACKS + bn * 16 + qdw;
    const unsigned short* xsrc = xbf + xrow * KTOT + k00 + xsl * 8;

    // W-tile write dword indices (loop-invariant): n = pc*8+j, swizzled k-slot
    int widx[8];
#pragma unroll
    for (int j = 0; j < 8; ++j) {
        const int n = pc * 8 + j;
        const int a = (n & 3) ^ ((n >> 2) & 3);
        widx[j] = n * 16 + (((t2 >> 2) ^ a) << 2) + (t2 & 3);
    }

    uint2 qreg[2];
    uint4 xreg[2];
    int zzc, zzn;
    float4 s0c, s1c, s0n, s1n;
    float sj[8], nzs[8];
    f32x4 acc[4][2] = {};

    // prologue: step-0 staging regs + group-0 scales
    qreg[0] = *reinterpret_cast<const uint2*>(qsrc);
    xreg[0] = *reinterpret_cast<const uint4*>(xsrc);
    {
        const int g = k00 >> 7;
        zzc = qz[g * PACKS + cg];
        s0c = *reinterpret_cast<const float4*>(sc + g * NN + cg * 8);
        s1c = *reinterpret_cast<const float4*>(sc + g * NN + cg * 8 + 4);
    }

#pragma unroll
    for (int st = 0; st < NSTEP; ++st) {
        const int B = st & 1, P = B ^ 1;

        // prefetch next step's staging into regs (stays in flight across barrier)
        if (st + 1 < NSTEP) {
            qreg[P] = *reinterpret_cast<const uint2*>(qsrc + (st + 1) * BK * PACKS);
            xreg[P] = *reinterpret_cast<const uint4*>(xsrc + (st + 1) * BK);
        }
        // prefetch next group's scales/zeros (group = 4 steps at BK=32)
        if ((st & 3) == 2 && st + 2 < NSTEP) {
            const int g = (k00 + (st + 2) * BK) >> 7;
            zzn = qz[g * PACKS + cg];
            s0n = *reinterpret_cast<const float4*>(sc + g * NN + cg * 8);
            s1n = *reinterpret_cast<const float4*>(sc + g * NN + cg * 8 + 4);
        }
        // expand scales/neg-zero-scale at each group boundary
        if ((st & 3) == 0) {
            if (st) { zzc = zzn; s0c = s0n; s1c = s1n; }
            const float sjl[8] = { s0c.x, s0c.y, s0c.z, s0c.w,
                                   s1c.x, s1c.y, s1c.z, s1c.w };
#pragma unroll
            for (int j = 0; j < 8; ++j) {
                const int sh = ((j >> 1) << 2) + ((j & 1) << 4);
                sj[j]  = sjl[j];
                nzs[j] = -(float)((zzc >> sh) & 0xF) * sjl[j];
            }
        }

        // staging writes (regs were loaded one step ago; compiler waits vmcnt here)
        *reinterpret_cast<uint2*>(&qst[B][qrow][qdw]) = qreg[B];
        *reinterpret_cast<uint4*>(&xst[B][xrow][(xsl ^ (xrow & 3)) << 2]) = xreg[B];

        // one barrier per step: drain LDS writes only, globals stay in flight
        asm volatile("s_waitcnt lgkmcnt(0)\n\ts_barrier" ::: "memory");

        // ---- dequant from staging (AWQ nibble order: sh = (j>>1)*4 + (j&1)*16) ----
        const int q0 = qst[B][2 * t2    ][wv * 4 + pc];
        const int q1 = qst[B][2 * t2 + 1][wv * 4 + pc];
        unsigned int* wbuf = &wtl[wv][B][0][0];
#pragma unroll
        for (int j = 0; j < 8; ++j) {
            const int sh = ((j >> 1) << 2) + ((j & 1) << 4);
            const float w0 = fmaf((float)((q0 >> sh) & 0xF), sj[j], nzs[j]);
            const float w1 = fmaf((float)((q1 >> sh) & 0xF), sj[j], nzs[j]);
            unsigned int pr;
            asm("v_cvt_pk_bf16_f32 %0, %1, %2" : "=v"(pr) : "v"(w0), "v"(w1));
            wbuf[widx[j]] = pr;     // (k even, k odd) pair, k-ascending in [n][k]
        }

        // ---- fragments + MFMA (wave-local lgkm ordering, no barrier) ----
        bf16x8 af[4], bfr[2];
#pragma unroll
        for (int mt = 0; mt < 4; ++mt) {
            const int r = mt * 16 + l15;
            af[mt] = *reinterpret_cast<const bf16x8*>(&xst[B][r][(l4 ^ (r & 3)) << 2]);
        }
#pragma unroll
        for (int nt = 0; nt < 2; ++nt) {
            const int n = nt * 16 + l15;
            const int a = (n & 3) ^ ((n >> 2) & 3);
            bfr[nt] = *reinterpret_cast<const bf16x8*>(&wtl[wv][B][n][(l4 ^ a) << 2]);
        }
#pragma unroll
        for (int mt = 0; mt < 4; ++mt) {
            acc[mt][0] = __builtin_amdgcn_mfma_f32_16x16x32_bf16(af[mt], bfr[0], acc[mt][0], 0, 0, 0);
            acc[mt][1] = __builtin_amdgcn_mfma_f32_16x16x32_bf16(af[mt], bfr[1], acc[mt][1], 0, 0, 0);
        }
    }

    // ---- epilogue: plain stores (C/D: col=lane&15, row=(lane>>4)*4+r) ----
    float* pout = part + ks * (MM * NN) + bn * BN + wv * 32;
#pragma unroll
    for (int mt = 0; mt < 4; ++mt)
#pragma unroll
        for (int nt = 0; nt < 2; ++nt) {
            const int r0 = mt * 16 + l4 * 4;
#pragma unroll
            for (int r = 0; r < 4; ++r)
                pout[(r0 + r) * NN + nt * 16 + l15] = acc[mt][nt][r];
        }
}

// reduce: out = bias + sum_ks part[ks]
__global__ __launch_bounds__(256) void reduce_k(const float* __restrict__ part,
                                                const float* __restrict__ bias,
                                                float* __restrict__ out) {
    const int t = blockIdx.x * 256 + threadIdx.x;   // float4 idx, 176128 total
    const int n = (t * 4) % NN;
    float4 s = reinterpret_cast<const float4*>(part)[t];
#pragma unroll
    for (int ks = 1; ks < KSPLIT; ++ks) {
        const float4 v = reinterpret_cast<const float4*>(part + ks * (MM * NN))[t];
        s.x += v.x; s.y += v.y; s.z += v.z; s.w += v.w;
    }
    const float4 b = *reinterpret_cast<const float4*>(bias + n);
    s.x += b.x; s.y += b.y; s.z += b.z; s.w += b.w;
    reinterpret_cast<float4*>(out)[t] = s;
}

extern "C" void kernel_launch(void* const* d_in, const int* in_sizes, int n_in,
                              void* d_out, int out_size, void* d_ws, size_t ws_size,
                              hipStream_t stream) {
    const float* x    = (const float*)d_in[0];
    const int*   qw   = (const int*)d_in[1];
    const int*   qz   = (const int*)d_in[2];
    const float* sc   = (const float*)d_in[3];
    const float* bias = (const float*)d_in[4];
    float* out = (float*)d_out;

    unsigned short* xbf = (unsigned short*)d_ws;                                  // 512 KB
    float* part = (float*)((char*)d_ws + MM * KTOT * sizeof(unsigned short));     // 22.5 MB

    prep<<<dim3(MM * KTOT / 8 / 256), 256, 0, stream>>>(x, xbf);
    awq_mfma<<<dim3(NBLOCKS), 256, 0, stream>>>(xbf, qw, qz, sc, part);
    reduce_k<<<dim3(MM * NN / 4 / 256), 256, 0, stream>>>(part, bias, out);
}